// Round 2
// baseline (18233.452 us; speedup 1.0000x reference)
//
#include <hip/hip_runtime.h>
#include <hip/hip_bf16.h>

#define T_LEN 8192
#define HD 256
#define D_EMB 300
#define NTAG 19
#define START_TAG 17
#define STOP_TAG 18

typedef unsigned long long u64;

__device__ __forceinline__ u64 a_load(const u64* p) {
  return __hip_atomic_load(p, __ATOMIC_RELAXED, __HIP_MEMORY_SCOPE_AGENT);
}
__device__ __forceinline__ void a_store(u64* p, u64 v) {
  __hip_atomic_store(p, v, __ATOMIC_RELAXED, __HIP_MEMORY_SCOPE_AGENT);
}

// ---------------- kernel 1: xg[dir][t][1024] = emb[sent] @ w_ih.T + b --------
__global__ __launch_bounds__(512) void k_xg(
    const int* __restrict__ sent, const float* __restrict__ emb,
    const float* __restrict__ w_ih_f, const float* __restrict__ b_f,
    const float* __restrict__ w_ih_b, const float* __restrict__ b_b,
    float* __restrict__ xg)
{
  const int dir = blockIdx.y;
  const int t0 = blockIdx.x * 16;
  const float* wih  = dir ? w_ih_b : w_ih_f;
  const float* bias = dir ? b_b    : b_f;
  __shared__ float xlds[16][304];   // 304*4B keeps rows 16B-aligned
  __shared__ int sid[16];
  const int tid = threadIdx.x;
  if (tid < 16) {
    int t = t0 + tid;
    int ts = dir ? (T_LEN - 1 - t) : t;   // backward consumes reversed input
    sid[tid] = sent[ts];
  }
  __syncthreads();
  for (int idx = tid; idx < 16 * D_EMB; idx += 512) {
    int r = idx / D_EMB, k = idx - r * D_EMB;
    xlds[r][k] = emb[(size_t)sid[r] * D_EMB + k];
  }
  __syncthreads();
  float* xgo = xg + (size_t)dir * T_LEN * 1024;
  for (int rr = 0; rr < 2; ++rr) {
    int row = tid + rr * 512;            // 0..1023
    const float* wrow = wih + (size_t)row * D_EMB;
    float acc[16];
    float bb = bias[row];
#pragma unroll
    for (int i = 0; i < 16; ++i) acc[i] = bb;
    for (int k4 = 0; k4 < 75; ++k4) {    // 300 = 75*4
      float4 w4 = *(const float4*)(wrow + k4 * 4);
#pragma unroll
      for (int i = 0; i < 16; ++i) {
        float4 x4 = *(const float4*)&xlds[i][k4 * 4];
        acc[i] = fmaf(w4.x, x4.x, acc[i]);
        acc[i] = fmaf(w4.y, x4.y, acc[i]);
        acc[i] = fmaf(w4.z, x4.z, acc[i]);
        acc[i] = fmaf(w4.w, x4.w, acc[i]);
      }
    }
#pragma unroll
    for (int i = 0; i < 16; ++i)
      xgo[(size_t)(t0 + i) * 1024 + row] = acc[i];
  }
}

// ---------------- kernel 2: the sequential BiLSTM recurrence -----------------
// 16 blocks: blk 0..7 = forward (chunk b), 8..15 = backward.
// Each block holds 128 rows of w_hh in registers; h exchanged through IC via
// DOUBLE-BUFFERED tag-embedded u64 atomic words: h-index i lives in slot i&1
// with tag i+1. Overwrite of a slot is gated through every reader's poll of
// that slot completing, so a poller only ever sees tag i-1 (stale) or i+1.
__global__ __launch_bounds__(256, 1) void k_lstm(
    const float* __restrict__ xg,
    const float* __restrict__ w_hh_f, const float* __restrict__ w_hh_b,
    const float* __restrict__ h0, const float* __restrict__ c0,
    float* __restrict__ h_out,          // [T][512]
    u64* __restrict__ hbuf)             // [2 dirs][2 slots][256]
{
  const int blk = blockIdx.x;
  const int dir = blk >> 3, b = blk & 7;
  const float* whh = dir ? w_hh_b : w_hh_f;
  const float* xgd = xg + (size_t)dir * T_LEN * 1024;
  u64* hb = hbuf + dir * 512;           // two 256-word slots
  const int tid = threadIdx.x;
  const int l = tid >> 1, half = tid & 1;   // row l, k-half
  const int g = l >> 5, jj = l & 31;        // gate, j within chunk
  const int rowg = g * 256 + b * 32 + jj;   // global gate-row

  float4 w[32];
  {
    const float* wr = whh + (size_t)rowg * 256 + half * 128;
#pragma unroll
    for (int kk = 0; kk < 32; ++kk) w[kk] = *(const float4*)(wr + kk * 4);
  }

  __shared__ float hlds[256];
  __shared__ float gbuf[128];

  float c = 0.f;
  if (tid < 32) {
    c = c0[dir * 256 + b * 32 + tid];
    float h0v = h0[dir * 256 + b * 32 + tid];
    // h-index 0 -> slot 0, tag 1
    a_store(hb + b * 32 + tid, ((u64)__float_as_uint(h0v) << 32) | 1ull);
  }
  float xgv = xgd[rowg];   // gate input for step 0

  for (int s = 0; s < T_LEN; ++s) {
    // consume h_s from slot s&1, tag s+1
    u64* wp = hb + (s & 1) * 256 + tid;
    const unsigned tag = (unsigned)(s + 1);
    u64 wv; int spins = 0;
    for (;;) {
      wv = a_load(wp);
      if ((unsigned)wv == tag) break;
      if (++spins > 8) __builtin_amdgcn_s_sleep(1);
    }
    hlds[tid] = __uint_as_float((unsigned)(wv >> 32));
    __syncthreads();

    float xgn = 0.f;
    if (s + 1 < T_LEN) xgn = xgd[(size_t)(s + 1) * 1024 + rowg];  // prefetch

    const float* hh = hlds + half * 128;
    float a0 = 0.f, a1 = 0.f, a2 = 0.f, a3 = 0.f;
#pragma unroll
    for (int kk = 0; kk < 32; ++kk) {
      float4 h4 = *(const float4*)(hh + kk * 4);
      a0 = fmaf(w[kk].x, h4.x, a0);
      a1 = fmaf(w[kk].y, h4.y, a1);
      a2 = fmaf(w[kk].z, h4.z, a2);
      a3 = fmaf(w[kk].w, h4.w, a3);
    }
    float dot = (a0 + a1) + (a2 + a3);
    dot += __shfl_xor(dot, 1);            // combine the two k-halves
    if (half == 0) gbuf[l] = dot + xgv;   // preactivation (xg already has bias)
    xgv = xgn;
    __syncthreads();

    if (tid < 32) {
      float pi = gbuf[tid], pf = gbuf[32 + tid], pg = gbuf[64 + tid], po = gbuf[96 + tid];
      float i_ = 1.f / (1.f + expf(-pi));
      float f_ = 1.f / (1.f + expf(-pf));
      float g_ = tanhf(pg);
      float o_ = 1.f / (1.f + expf(-po));
      c = f_ * c + i_ * g_;
      float h = o_ * tanhf(c);
      int tor = dir ? (T_LEN - 1 - s) : s;
      h_out[(size_t)tor * 512 + dir * 256 + b * 32 + tid] = h;
      // produce h_{s+1} -> slot (s+1)&1, tag s+2
      a_store(hb + ((s + 1) & 1) * 256 + b * 32 + tid,
              ((u64)__float_as_uint(h) << 32) | (u64)(unsigned)(s + 2));
    }
  }
}

// ---------------- kernel 3: feats[t][19] = [hf,hb] @ w_out.T + b_out ---------
__global__ __launch_bounds__(640) void k_feats(
    const float* __restrict__ h, const float* __restrict__ w_out,
    const float* __restrict__ b_out, float* __restrict__ feats)
{
  const int tid = threadIdx.x;
  if (tid >= 32 * NTAG) return;
  const int tloc = tid / NTAG, j = tid - tloc * NTAG;
  const int t = blockIdx.x * 32 + tloc;
  const float* hr = h + (size_t)t * 512;
  const float* wr = w_out + (size_t)j * 512;
  float a0 = 0.f, a1 = 0.f, a2 = 0.f, a3 = 0.f;
  for (int k = 0; k < 512; k += 4) {
    float4 hv = *(const float4*)(hr + k);
    float4 wv = *(const float4*)(wr + k);
    a0 = fmaf(hv.x, wv.x, a0);
    a1 = fmaf(hv.y, wv.y, a1);
    a2 = fmaf(hv.z, wv.z, a2);
    a3 = fmaf(hv.w, wv.w, a3);
  }
  feats[(size_t)t * NTAG + j] = ((a0 + a1) + (a2 + a3)) + b_out[j];
}

// ---------------- kernel 4: sequential Viterbi forward (exact ops) -----------
// wave0: lanes j (<19) own p in [0,10), lanes 32+j own p in [10,19).
// wave1: double-buffer prefetch of feats chunks (256 steps each).
__global__ __launch_bounds__(128) void k_viterbi(
    const float* __restrict__ feats, const float* __restrict__ trans,
    float* __restrict__ fvfinal, unsigned char* __restrict__ bps)
{
  __shared__ float fchunk[2][256 * NTAG];
  __shared__ float fv[32];
  const int tid = threadIdx.x;

  const int lo = (tid < 32) ? 1 : 0;
  const int j = (tid < 64) ? (lo ? tid : tid - 32) : 0;
  const int jc = (j < NTAG) ? j : NTAG - 1;
  const int plo = lo ? 0 : 10;
  float tr[10];
  if (tid < 64) {
#pragma unroll
    for (int q = 0; q < 10; ++q) {
      int p = plo + q;
      tr[q] = (p < NTAG) ? trans[jc * NTAG + p] : -3.0e38f;
    }
    if (tid < NTAG) fv[tid] = (tid == START_TAG) ? 0.f : -10000.f;
  }

  for (int cc = -1; cc < 32; ++cc) {
    if (tid >= 64) {
      // loader wave: load chunk cc+1
      if (cc + 1 < 32) {
        const float* src = feats + (size_t)(cc + 1) * 256 * NTAG;
        float* dst = fchunk[(cc + 1) & 1];
        for (int idx = tid - 64; idx < 256 * NTAG; idx += 64) dst[idx] = src[idx];
      }
    } else if (cc >= 0) {
      const float* fc = fchunk[cc & 1];
      for (int i = 0; i < 256; ++i) {
        float best = -3.0e38f; int bi = 0;
#pragma unroll
        for (int q = 0; q < 10; ++q) {
          int p = plo + q;
          float s = (p < NTAG) ? (fv[p] + tr[q]) : -3.0e38f;
          bool gt = s > best;              // strict >: first-max tie rule
          best = gt ? s : best;
          bi = gt ? p : bi;
        }
        float ob = __shfl_xor(best, 32);
        int obi = __shfl_xor(bi, 32);
        bool take = lo ? (ob > best) : !(best > ob);  // ties -> smaller p
        if (take) { best = ob; bi = obi; }
        int t = cc * 256 + i;
        if (tid < NTAG) {
          float fnew = best + fc[i * NTAG + tid];
          bps[(size_t)t * NTAG + tid] = (unsigned char)bi;
          fv[tid] = fnew;
        }
        __builtin_amdgcn_wave_barrier();   // LDS write->read fence within wave
      }
    }
    __syncthreads();
  }
  if (tid < NTAG) fvfinal[tid] = fv[tid];
}

// ---------------- kernel 5: exact parallel backtrack via chunk composition ---
__global__ __launch_bounds__(1024) void k_backtrack(
    const float* __restrict__ fvfinal, const float* __restrict__ trans,
    const unsigned char* __restrict__ bps, float* __restrict__ out)
{
  __shared__ unsigned char maps[64][20];
  __shared__ unsigned char xc[64];     // end-of-chunk tag for each chunk
  __shared__ float score_sh;
  const int tid = threadIdx.x;

  // phase 1: per-(chunk, start-tag) walks: 64 chunks x 19 tags
  for (int jid = tid; jid < 64 * NTAG; jid += 1024) {
    int c = jid / NTAG, tau = jid - c * NTAG;
    int y = tau;
    for (int t = (c + 1) * 128 - 1; t >= c * 128; --t)
      y = bps[(size_t)t * NTAG + y];
    maps[c][tau] = (unsigned char)y;
  }
  __syncthreads();

  // phase 2: terminal argmax + chunk-boundary composition (thread 0)
  if (tid == 0) {
    float best = -3.0e38f; int bi = 0;
    for (int p = 0; p < NTAG; ++p) {
      float s = fvfinal[p] + trans[STOP_TAG * NTAG + p];
      if (s > best) { best = s; bi = p; }
    }
    score_sh = best;
    int e = bi;                          // path[8191]
    for (int c = 63; c >= 0; --c) { xc[c] = (unsigned char)e; e = maps[c][e]; }
  }
  __syncthreads();

  // phase 3: emit (one thread per chunk)
  if (tid == 0) out[0] = score_sh;
  if (tid < 64) {
    int c = tid;
    int y = xc[c];
    out[1 + ((c + 1) * 128 - 1)] = (float)y;
    for (int t = (c + 1) * 128 - 1; t > c * 128; --t) {
      y = bps[(size_t)t * NTAG + y];
      out[1 + t - 1] = (float)y;
    }
  }
}

// -----------------------------------------------------------------------------
extern "C" void kernel_launch(void* const* d_in, const int* in_sizes, int n_in,
                              void* d_out, int out_size, void* d_ws, size_t ws_size,
                              hipStream_t stream) {
  const int*   sent    = (const int*)d_in[0];
  const float* emb     = (const float*)d_in[1];
  const float* w_ih_f  = (const float*)d_in[2];
  const float* w_hh_f  = (const float*)d_in[3];
  const float* b_f     = (const float*)d_in[4];
  const float* w_ih_b  = (const float*)d_in[5];
  const float* w_hh_b  = (const float*)d_in[6];
  const float* b_b     = (const float*)d_in[7];
  const float* w_out   = (const float*)d_in[8];
  const float* b_out   = (const float*)d_in[9];
  const float* trans   = (const float*)d_in[10];
  const float* h0      = (const float*)d_in[11];
  const float* c0      = (const float*)d_in[12];
  float* out = (float*)d_out;

  char* ws = (char*)d_ws;
  float* xg            = (float*)(ws + 0);           // 2*T*1024 f32 = 64 MiB
  float* h_out         = (float*)(ws + 67108864);    // T*512 f32   = 16 MiB
  float* feats         = (float*)(ws + 83886080);    // T*19 f32
  float* fvfin         = (float*)(ws + 84508672);    // 32 f32
  unsigned char* bps   = (unsigned char*)(ws + 84508800);  // T*19 u8
  u64* hbuf            = (u64*)(ws + 84664448);      // 2 dirs * 2 slots * 256 u64

  // reset the tag words so step-tag polling starts clean every call/replay
  hipMemsetAsync(hbuf, 0, 1024 * sizeof(u64), stream);

  k_xg      <<<dim3(512, 2), 512, 0, stream>>>(sent, emb, w_ih_f, b_f, w_ih_b, b_b, xg);
  k_lstm    <<<16, 256, 0, stream>>>(xg, w_hh_f, w_hh_b, h0, c0, h_out, hbuf);
  k_feats   <<<256, 640, 0, stream>>>(h_out, w_out, b_out, feats);
  k_viterbi <<<1, 128, 0, stream>>>(feats, trans, fvfin, bps);
  k_backtrack<<<1, 1024, 0, stream>>>(fvfin, trans, bps, out);
}

// Round 3
// 17844.856 us; speedup vs baseline: 1.0218x; 1.0218x over previous
//
#include <hip/hip_runtime.h>
#include <hip/hip_bf16.h>

#define T_LEN 8192
#define HD 256
#define D_EMB 300
#define NTAG 19
#define START_TAG 17
#define STOP_TAG 18

typedef unsigned long long u64;

__device__ __forceinline__ u64 a_load(const u64* p) {
  return __hip_atomic_load(p, __ATOMIC_RELAXED, __HIP_MEMORY_SCOPE_AGENT);
}
__device__ __forceinline__ void a_store(u64* p, u64 v) {
  __hip_atomic_store(p, v, __ATOMIC_RELAXED, __HIP_MEMORY_SCOPE_AGENT);
}

// ---------------- kernel 1: xg[dir][t][1024] = emb[sent] @ w_ih.T + b --------
__global__ __launch_bounds__(512) void k_xg(
    const int* __restrict__ sent, const float* __restrict__ emb,
    const float* __restrict__ w_ih_f, const float* __restrict__ b_f,
    const float* __restrict__ w_ih_b, const float* __restrict__ b_b,
    float* __restrict__ xg)
{
  const int dir = blockIdx.y;
  const int t0 = blockIdx.x * 16;
  const float* wih  = dir ? w_ih_b : w_ih_f;
  const float* bias = dir ? b_b    : b_f;
  __shared__ float xlds[16][304];   // 304*4B keeps rows 16B-aligned
  __shared__ int sid[16];
  const int tid = threadIdx.x;
  if (tid < 16) {
    int t = t0 + tid;
    int ts = dir ? (T_LEN - 1 - t) : t;   // backward consumes reversed input
    sid[tid] = sent[ts];
  }
  __syncthreads();
  for (int idx = tid; idx < 16 * D_EMB; idx += 512) {
    int r = idx / D_EMB, k = idx - r * D_EMB;
    xlds[r][k] = emb[(size_t)sid[r] * D_EMB + k];
  }
  __syncthreads();
  float* xgo = xg + (size_t)dir * T_LEN * 1024;
  for (int rr = 0; rr < 2; ++rr) {
    int row = tid + rr * 512;            // 0..1023
    const float* wrow = wih + (size_t)row * D_EMB;
    float acc[16];
    float bb = bias[row];
#pragma unroll
    for (int i = 0; i < 16; ++i) acc[i] = bb;
    for (int k4 = 0; k4 < 75; ++k4) {    // 300 = 75*4
      float4 w4 = *(const float4*)(wrow + k4 * 4);
#pragma unroll
      for (int i = 0; i < 16; ++i) {
        float4 x4 = *(const float4*)&xlds[i][k4 * 4];
        acc[i] = fmaf(w4.x, x4.x, acc[i]);
        acc[i] = fmaf(w4.y, x4.y, acc[i]);
        acc[i] = fmaf(w4.z, x4.z, acc[i]);
        acc[i] = fmaf(w4.w, x4.w, acc[i]);
      }
    }
#pragma unroll
    for (int i = 0; i < 16; ++i)
      xgo[(size_t)(t0 + i) * 1024 + row] = acc[i];
  }
}

// ---------------- kernel 2: the sequential BiLSTM recurrence -----------------
// 16 blocks: blk 0..7 = forward (chunk b of h), 8..15 = backward.
// h-element j is owned by a 16-lane group inside ONE wave: thread (j, q) holds
// gate-rows {g*256+j} x cols [16q,16q+16) in 64 VGPRs. Per step: one poll of
// remote h-words (double-buffered tag-embedded u64, slot = s&1, tag = s+1),
// ONE __syncthreads, dot + 4-round shfl_xor reduce, activation in-wave (q==0),
// LDS write of own h for next step + IC store for remote blocks.
__global__ __launch_bounds__(512, 1) void k_lstm(
    const float* __restrict__ xg,
    const float* __restrict__ w_hh_f, const float* __restrict__ w_hh_b,
    const float* __restrict__ h0, const float* __restrict__ c0,
    float* __restrict__ h_out,          // [T][512]
    u64* __restrict__ hbuf)             // [2 dirs][2 slots][256]
{
  const int blk = blockIdx.x;
  const int dir = blk >> 3, b = blk & 7;
  const float* whh = dir ? w_hh_b : w_hh_f;
  const float* xgd = xg + (size_t)dir * T_LEN * 1024;
  u64* hb = hbuf + dir * 512;
  const int tid = threadIdx.x;
  const int jl = tid >> 4, q = tid & 15;     // j-local 0..31, col-group 0..15
  const int j = b * 32 + jl;                 // global h index 0..255
  const bool isq0 = (q == 0);

  // weights: rows {g*256+j}, cols [16q,16q+16)  -> 16 float4 = 64 VGPR
  float4 w[4][4];
#pragma unroll
  for (int g = 0; g < 4; ++g) {
    const float* wr = whh + (size_t)(g * 256 + j) * 256 + q * 16;
#pragma unroll
    for (int kk = 0; kk < 4; ++kk) w[g][kk] = *(const float4*)(wr + kk * 4);
  }

  __shared__ float hlds[2][256];

  float c = 0.f;
  float x0 = 0.f, x1 = 0.f, x2 = 0.f, x3 = 0.f;
  if (isq0) {
    c = c0[dir * 256 + j];
    float h0v = h0[dir * 256 + j];
    hlds[0][j] = h0v;                                   // own word via LDS
    a_store(hb + j, ((u64)__float_as_uint(h0v) << 32) | 1ull);  // for remotes
    x0 = xgd[j]; x1 = xgd[256 + j]; x2 = xgd[512 + j]; x3 = xgd[768 + j];
  }

  // dual pollers: tid and tid+256 poll the same word (same-value WAW is benign)
  const int ptid = tid & 255;
  const bool pollme = ((ptid >> 5) != b);
  u64* pollbase = hb + ptid;

  for (int s = 0; s < T_LEN; ++s) {
    const int slot = s & 1;
    if (pollme) {
      u64* wp = pollbase + slot * 256;
      const unsigned tag = (unsigned)(s + 1);
      u64 wv;
      do { wv = a_load(wp); } while ((unsigned)wv != tag);
      hlds[slot][ptid] = __uint_as_float((unsigned)(wv >> 32));
    }
    __syncthreads();

    // prefetch next step's xg (independent, overlaps the dot)
    float n0 = 0.f, n1 = 0.f, n2 = 0.f, n3 = 0.f;
    if (isq0 && s + 1 < T_LEN) {
      const float* xr = xgd + (size_t)(s + 1) * 1024;
      n0 = xr[j]; n1 = xr[256 + j]; n2 = xr[512 + j]; n3 = xr[768 + j];
    }

    const float* hv = hlds[slot] + q * 16;
    float a0 = 0.f, a1 = 0.f, a2 = 0.f, a3 = 0.f;
#pragma unroll
    for (int kk = 0; kk < 4; ++kk) {
      float4 h4 = *(const float4*)(hv + kk * 4);
      a0 = fmaf(w[0][kk].x, h4.x, a0); a0 = fmaf(w[0][kk].y, h4.y, a0);
      a0 = fmaf(w[0][kk].z, h4.z, a0); a0 = fmaf(w[0][kk].w, h4.w, a0);
      a1 = fmaf(w[1][kk].x, h4.x, a1); a1 = fmaf(w[1][kk].y, h4.y, a1);
      a1 = fmaf(w[1][kk].z, h4.z, a1); a1 = fmaf(w[1][kk].w, h4.w, a1);
      a2 = fmaf(w[2][kk].x, h4.x, a2); a2 = fmaf(w[2][kk].y, h4.y, a2);
      a2 = fmaf(w[2][kk].z, h4.z, a2); a2 = fmaf(w[2][kk].w, h4.w, a2);
      a3 = fmaf(w[3][kk].x, h4.x, a3); a3 = fmaf(w[3][kk].y, h4.y, a3);
      a3 = fmaf(w[3][kk].z, h4.z, a3); a3 = fmaf(w[3][kk].w, h4.w, a3);
    }
#pragma unroll
    for (int m = 1; m < 16; m <<= 1) {
      a0 += __shfl_xor(a0, m);
      a1 += __shfl_xor(a1, m);
      a2 += __shfl_xor(a2, m);
      a3 += __shfl_xor(a3, m);
    }

    if (isq0) {
      float pi = a0 + x0, pf = a1 + x1, pg = a2 + x2, po = a3 + x3;
      float i_ = 1.f / (1.f + expf(-pi));
      float f_ = 1.f / (1.f + expf(-pf));
      float g_ = tanhf(pg);
      float o_ = 1.f / (1.f + expf(-po));
      c = f_ * c + i_ * g_;
      float h = o_ * tanhf(c);
      int tor = dir ? (T_LEN - 1 - s) : s;
      h_out[(size_t)tor * 512 + dir * 256 + j] = h;
      hlds[slot ^ 1][j] = h;                            // own word via LDS
      a_store(hb + (slot ^ 1) * 256 + j,
              ((u64)__float_as_uint(h) << 32) | (u64)(unsigned)(s + 2));
    }
    x0 = n0; x1 = n1; x2 = n2; x3 = n3;
  }
}

// ---------------- kernel 3: feats[t][19] = [hf,hb] @ w_out.T + b_out ---------
__global__ __launch_bounds__(640) void k_feats(
    const float* __restrict__ h, const float* __restrict__ w_out,
    const float* __restrict__ b_out, float* __restrict__ feats)
{
  const int tid = threadIdx.x;
  if (tid >= 32 * NTAG) return;
  const int tloc = tid / NTAG, j = tid - tloc * NTAG;
  const int t = blockIdx.x * 32 + tloc;
  const float* hr = h + (size_t)t * 512;
  const float* wr = w_out + (size_t)j * 512;
  float a0 = 0.f, a1 = 0.f, a2 = 0.f, a3 = 0.f;
  for (int k = 0; k < 512; k += 4) {
    float4 hv = *(const float4*)(hr + k);
    float4 wv = *(const float4*)(wr + k);
    a0 = fmaf(hv.x, wv.x, a0);
    a1 = fmaf(hv.y, wv.y, a1);
    a2 = fmaf(hv.z, wv.z, a2);
    a3 = fmaf(hv.w, wv.w, a3);
  }
  feats[(size_t)t * NTAG + j] = ((a0 + a1) + (a2 + a3)) + b_out[j];
}

// ---------------- kernel 4: sequential Viterbi forward (exact ops) -----------
// wave0: lanes j (<19) own p in [0,10), lanes 32+j own p in [10,19).
// wave1: double-buffer prefetch of feats chunks (256 steps each).
__global__ __launch_bounds__(128) void k_viterbi(
    const float* __restrict__ feats, const float* __restrict__ trans,
    float* __restrict__ fvfinal, unsigned char* __restrict__ bps)
{
  __shared__ float fchunk[2][256 * NTAG];
  __shared__ float fv[32];
  const int tid = threadIdx.x;

  const int lo = (tid < 32) ? 1 : 0;
  const int j = (tid < 64) ? (lo ? tid : tid - 32) : 0;
  const int jc = (j < NTAG) ? j : NTAG - 1;
  const int plo = lo ? 0 : 10;
  float tr[10];
  if (tid < 64) {
#pragma unroll
    for (int q = 0; q < 10; ++q) {
      int p = plo + q;
      tr[q] = (p < NTAG) ? trans[jc * NTAG + p] : -3.0e38f;
    }
    if (tid < NTAG) fv[tid] = (tid == START_TAG) ? 0.f : -10000.f;
  }

  for (int cc = -1; cc < 32; ++cc) {
    if (tid >= 64) {
      // loader wave: load chunk cc+1
      if (cc + 1 < 32) {
        const float* src = feats + (size_t)(cc + 1) * 256 * NTAG;
        float* dst = fchunk[(cc + 1) & 1];
        for (int idx = tid - 64; idx < 256 * NTAG; idx += 64) dst[idx] = src[idx];
      }
    } else if (cc >= 0) {
      const float* fc = fchunk[cc & 1];
      for (int i = 0; i < 256; ++i) {
        float best = -3.0e38f; int bi = 0;
#pragma unroll
        for (int q = 0; q < 10; ++q) {
          int p = plo + q;
          float s = (p < NTAG) ? (fv[p] + tr[q]) : -3.0e38f;
          bool gt = s > best;              // strict >: first-max tie rule
          best = gt ? s : best;
          bi = gt ? p : bi;
        }
        float ob = __shfl_xor(best, 32);
        int obi = __shfl_xor(bi, 32);
        bool take = lo ? (ob > best) : !(best > ob);  // ties -> smaller p
        if (take) { best = ob; bi = obi; }
        int t = cc * 256 + i;
        if (tid < NTAG) {
          float fnew = best + fc[i * NTAG + tid];
          bps[(size_t)t * NTAG + tid] = (unsigned char)bi;
          fv[tid] = fnew;
        }
        __builtin_amdgcn_wave_barrier();   // LDS write->read fence within wave
      }
    }
    __syncthreads();
  }
  if (tid < NTAG) fvfinal[tid] = fv[tid];
}

// ---------------- kernel 5: exact parallel backtrack via chunk composition ---
__global__ __launch_bounds__(1024) void k_backtrack(
    const float* __restrict__ fvfinal, const float* __restrict__ trans,
    const unsigned char* __restrict__ bps, float* __restrict__ out)
{
  __shared__ unsigned char maps[64][20];
  __shared__ unsigned char xc[64];     // end-of-chunk tag for each chunk
  __shared__ float score_sh;
  const int tid = threadIdx.x;

  // phase 1: per-(chunk, start-tag) walks: 64 chunks x 19 tags
  for (int jid = tid; jid < 64 * NTAG; jid += 1024) {
    int c = jid / NTAG, tau = jid - c * NTAG;
    int y = tau;
    for (int t = (c + 1) * 128 - 1; t >= c * 128; --t)
      y = bps[(size_t)t * NTAG + y];
    maps[c][tau] = (unsigned char)y;
  }
  __syncthreads();

  // phase 2: terminal argmax + chunk-boundary composition (thread 0)
  if (tid == 0) {
    float best = -3.0e38f; int bi = 0;
    for (int p = 0; p < NTAG; ++p) {
      float s = fvfinal[p] + trans[STOP_TAG * NTAG + p];
      if (s > best) { best = s; bi = p; }
    }
    score_sh = best;
    int e = bi;                          // path[8191]
    for (int c = 63; c >= 0; --c) { xc[c] = (unsigned char)e; e = maps[c][e]; }
  }
  __syncthreads();

  // phase 3: emit (one thread per chunk)
  if (tid == 0) out[0] = score_sh;
  if (tid < 64) {
    int c = tid;
    int y = xc[c];
    out[1 + ((c + 1) * 128 - 1)] = (float)y;
    for (int t = (c + 1) * 128 - 1; t > c * 128; --t) {
      y = bps[(size_t)t * NTAG + y];
      out[1 + t - 1] = (float)y;
    }
  }
}

// -----------------------------------------------------------------------------
extern "C" void kernel_launch(void* const* d_in, const int* in_sizes, int n_in,
                              void* d_out, int out_size, void* d_ws, size_t ws_size,
                              hipStream_t stream) {
  const int*   sent    = (const int*)d_in[0];
  const float* emb     = (const float*)d_in[1];
  const float* w_ih_f  = (const float*)d_in[2];
  const float* w_hh_f  = (const float*)d_in[3];
  const float* b_f     = (const float*)d_in[4];
  const float* w_ih_b  = (const float*)d_in[5];
  const float* w_hh_b  = (const float*)d_in[6];
  const float* b_b     = (const float*)d_in[7];
  const float* w_out   = (const float*)d_in[8];
  const float* b_out   = (const float*)d_in[9];
  const float* trans   = (const float*)d_in[10];
  const float* h0      = (const float*)d_in[11];
  const float* c0      = (const float*)d_in[12];
  float* out = (float*)d_out;

  char* ws = (char*)d_ws;
  float* xg            = (float*)(ws + 0);           // 2*T*1024 f32 = 64 MiB
  float* h_out         = (float*)(ws + 67108864);    // T*512 f32   = 16 MiB
  float* feats         = (float*)(ws + 83886080);    // T*19 f32
  float* fvfin         = (float*)(ws + 84508672);    // 32 f32
  unsigned char* bps   = (unsigned char*)(ws + 84508800);  // T*19 u8
  u64* hbuf            = (u64*)(ws + 84664448);      // 2 dirs * 2 slots * 256 u64

  // reset the tag words so step-tag polling starts clean every call/replay
  hipMemsetAsync(hbuf, 0, 1024 * sizeof(u64), stream);

  k_xg      <<<dim3(512, 2), 512, 0, stream>>>(sent, emb, w_ih_f, b_f, w_ih_b, b_b, xg);
  k_lstm    <<<16, 512, 0, stream>>>(xg, w_hh_f, w_hh_b, h0, c0, h_out, hbuf);
  k_feats   <<<256, 640, 0, stream>>>(h_out, w_out, b_out, feats);
  k_viterbi <<<1, 128, 0, stream>>>(feats, trans, fvfin, bps);
  k_backtrack<<<1, 1024, 0, stream>>>(fvfin, trans, bps, out);
}

// Round 5
// 16763.698 us; speedup vs baseline: 1.0877x; 1.0645x over previous
//
#include <hip/hip_runtime.h>
#include <hip/hip_bf16.h>

#define T_LEN 8192
#define HD 256
#define D_EMB 300
#define NTAG 19
#define START_TAG 17
#define STOP_TAG 18

typedef unsigned long long u64;

__device__ __forceinline__ u64 a_load(const u64* p) {
  return __hip_atomic_load(p, __ATOMIC_RELAXED, __HIP_MEMORY_SCOPE_AGENT);
}
__device__ __forceinline__ void a_store(u64* p, u64 v) {
  __hip_atomic_store(p, v, __ATOMIC_RELAXED, __HIP_MEMORY_SCOPE_AGENT);
}
// un-sinkable vector load: forces weights to stay materialized in VGPRs
__device__ __forceinline__ float4 ld4(const float* p) {
  float4 v;
  asm volatile("global_load_dwordx4 %0, %1, off\n\ts_waitcnt vmcnt(0)"
               : "=&v"(v) : "v"(p));
  return v;
}
__device__ __forceinline__ float rcp_(float x) { return __builtin_amdgcn_rcpf(x); }

#define HIDX(i) (((i) >> 4) * 20 + ((i) & 15))  // stride-20 swizzle: 2-way max (free)

// ---------------- kernel 1: xg[dir][t][1024] = emb[sent] @ w_ih.T + b --------
__global__ __launch_bounds__(512) void k_xg(
    const int* __restrict__ sent, const float* __restrict__ emb,
    const float* __restrict__ w_ih_f, const float* __restrict__ b_f,
    const float* __restrict__ w_ih_b, const float* __restrict__ b_b,
    float* __restrict__ xg)
{
  const int dir = blockIdx.y;
  const int t0 = blockIdx.x * 16;
  const float* wih  = dir ? w_ih_b : w_ih_f;
  const float* bias = dir ? b_b    : b_f;
  __shared__ float xlds[16][304];
  __shared__ int sid[16];
  const int tid = threadIdx.x;
  if (tid < 16) {
    int t = t0 + tid;
    int ts = dir ? (T_LEN - 1 - t) : t;
    sid[tid] = sent[ts];
  }
  __syncthreads();
  for (int idx = tid; idx < 16 * D_EMB; idx += 512) {
    int r = idx / D_EMB, k = idx - r * D_EMB;
    xlds[r][k] = emb[(size_t)sid[r] * D_EMB + k];
  }
  __syncthreads();
  float* xgo = xg + (size_t)dir * T_LEN * 1024;
  for (int rr = 0; rr < 2; ++rr) {
    int row = tid + rr * 512;
    const float* wrow = wih + (size_t)row * D_EMB;
    float acc[16];
    float bb = bias[row];
#pragma unroll
    for (int i = 0; i < 16; ++i) acc[i] = bb;
    for (int k4 = 0; k4 < 75; ++k4) {
      float4 w4 = *(const float4*)(wrow + k4 * 4);
#pragma unroll
      for (int i = 0; i < 16; ++i) {
        float4 x4 = *(const float4*)&xlds[i][k4 * 4];
        acc[i] = fmaf(w4.x, x4.x, acc[i]);
        acc[i] = fmaf(w4.y, x4.y, acc[i]);
        acc[i] = fmaf(w4.z, x4.z, acc[i]);
        acc[i] = fmaf(w4.w, x4.w, acc[i]);
      }
    }
#pragma unroll
    for (int i = 0; i < 16; ++i)
      xgo[(size_t)(t0 + i) * 1024 + row] = acc[i];
  }
}

// ---------------- kernel 2: the sequential BiLSTM recurrence -----------------
// 16 blocks (proven r2/r3 protocol): blk 0..7 = fwd chunk b, 8..15 = bwd.
// Per step: 224 poll lanes depth-2-pipeline-poll the 224 remote tag-words
// (slot = s&1, tag = s+1), write values into swizzled LDS; one barrier; each
// lane's 64-FMA dot + 4-round shfl reduce; q0 lanes run activations and
// publish h (a_store FIRST, then h_out/LDS).
__global__ __launch_bounds__(512, 1) void k_lstm(
    const float* __restrict__ xg,
    const float* __restrict__ w_hh_f, const float* __restrict__ w_hh_b,
    const float* __restrict__ h0, const float* __restrict__ c0,
    float* __restrict__ h_out,          // [T][512]
    u64* __restrict__ hbuf)             // [2 dirs][2 slots][256]
{
  const int blk = blockIdx.x;
  const int dir = blk >> 3, b = blk & 7;
  const float* whh = dir ? w_hh_b : w_hh_f;
  const float* xgd = xg + (size_t)dir * T_LEN * 1024;
  u64* hb = hbuf + dir * 512;
  const int tid = threadIdx.x;
  const int jl = tid >> 4, q = tid & 15;     // j-local 0..31, col-group 0..15
  const int j = b * 32 + jl;                 // global h index 0..255
  const bool isq0 = (q == 0);

  // poll mapping: tid<224 -> remote chunk c (skipping own b), word tid&31
  const bool ispoll = (tid < 224);
  int pwi = 0;
  {
    int c = tid >> 5;
    pwi = (c + (c >= b)) * 32 + (tid & 31);
  }

  // weights: rows {g*256+j}, cols [16q,16q+16) -> 16 float4 pinned in VGPRs
  float4 w[4][4];
#pragma unroll
  for (int g = 0; g < 4; ++g) {
    const float* wr = whh + (size_t)(g * 256 + j) * 256 + q * 16;
#pragma unroll
    for (int kk = 0; kk < 4; ++kk) w[g][kk] = ld4(wr + kk * 4);
  }

  __shared__ float hlds[2][320];   // swizzled: h[i] at HIDX(i)

  float c = 0.f;
  float x0 = 0.f, x1 = 0.f, x2 = 0.f, x3 = 0.f;
  if (isq0) {
    c = c0[dir * 256 + j];
    float h0v = h0[dir * 256 + j];
    hlds[0][HIDX(j)] = h0v;                              // own word via LDS
    a_store(hb + j, ((u64)__float_as_uint(h0v) << 32) | 1ull);  // for remotes
    x0 = xgd[j]; x1 = xgd[256 + j]; x2 = xgd[512 + j]; x3 = xgd[768 + j];
  }

  for (int s = 0; s < T_LEN; ++s) {
    const int slot = s & 1;
    if (ispoll) {
      u64* wp = hb + slot * 256 + pwi;
      const unsigned tag = (unsigned)(s + 1);
      // depth-2 pipelined poll: issue next load before checking previous
      u64 cur = a_load(wp);
      u64 nxt = a_load(wp);
      while ((unsigned)cur != tag) {
        cur = nxt;
        nxt = a_load(wp);
      }
      hlds[slot][HIDX(pwi)] = __uint_as_float((unsigned)(cur >> 32));
    }
    __syncthreads();

    // prefetch next step's xg (independent, overlaps the dot)
    float n0 = 0.f, n1 = 0.f, n2 = 0.f, n3 = 0.f;
    if (isq0 && s + 1 < T_LEN) {
      const float* xr = xgd + (size_t)(s + 1) * 1024;
      n0 = xr[j]; n1 = xr[256 + j]; n2 = xr[512 + j]; n3 = xr[768 + j];
    }

    const float* hv = hlds[slot] + q * 20;
    float a0 = 0.f, a1 = 0.f, a2 = 0.f, a3 = 0.f;
#pragma unroll
    for (int kk = 0; kk < 4; ++kk) {
      float4 h4 = *(const float4*)(hv + kk * 4);
      a0 = fmaf(w[0][kk].x, h4.x, a0); a0 = fmaf(w[0][kk].y, h4.y, a0);
      a0 = fmaf(w[0][kk].z, h4.z, a0); a0 = fmaf(w[0][kk].w, h4.w, a0);
      a1 = fmaf(w[1][kk].x, h4.x, a1); a1 = fmaf(w[1][kk].y, h4.y, a1);
      a1 = fmaf(w[1][kk].z, h4.z, a1); a1 = fmaf(w[1][kk].w, h4.w, a1);
      a2 = fmaf(w[2][kk].x, h4.x, a2); a2 = fmaf(w[2][kk].y, h4.y, a2);
      a2 = fmaf(w[2][kk].z, h4.z, a2); a2 = fmaf(w[2][kk].w, h4.w, a2);
      a3 = fmaf(w[3][kk].x, h4.x, a3); a3 = fmaf(w[3][kk].y, h4.y, a3);
      a3 = fmaf(w[3][kk].z, h4.z, a3); a3 = fmaf(w[3][kk].w, h4.w, a3);
    }
#pragma unroll
    for (int m = 1; m < 16; m <<= 1) {
      a0 += __shfl_xor(a0, m);
      a1 += __shfl_xor(a1, m);
      a2 += __shfl_xor(a2, m);
      a3 += __shfl_xor(a3, m);
    }

    if (isq0) {
      float pi = a0 + x0, pf = a1 + x1, pg = a2 + x2, po = a3 + x3;
      float i_ = rcp_(1.f + __expf(-pi));
      float f_ = rcp_(1.f + __expf(-pf));
      float o_ = rcp_(1.f + __expf(-po));
      float eg = __expf(2.f * fabsf(pg));
      float g_ = copysignf(1.f - 2.f * rcp_(1.f + eg), pg);
      c = f_ * c + i_ * g_;
      float ec = __expf(2.f * fabsf(c));
      float th = copysignf(1.f - 2.f * rcp_(1.f + ec), c);
      float h = o_ * th;
      // publish FIRST (critical path), then local/global bookkeeping
      a_store(hb + (slot ^ 1) * 256 + j,
              ((u64)__float_as_uint(h) << 32) | (u64)(unsigned)(s + 2));
      hlds[slot ^ 1][HIDX(j)] = h;
      int tor = dir ? (T_LEN - 1 - s) : s;
      h_out[(size_t)tor * 512 + dir * 256 + j] = h;
    }
    x0 = n0; x1 = n1; x2 = n2; x3 = n3;
  }
}

// ---------------- kernel 3: feats[t][19] = [hf,hb] @ w_out.T + b_out ---------
__global__ __launch_bounds__(640) void k_feats(
    const float* __restrict__ h, const float* __restrict__ w_out,
    const float* __restrict__ b_out, float* __restrict__ feats)
{
  const int tid = threadIdx.x;
  if (tid >= 32 * NTAG) return;
  const int tloc = tid / NTAG, j = tid - tloc * NTAG;
  const int t = blockIdx.x * 32 + tloc;
  const float* hr = h + (size_t)t * 512;
  const float* wr = w_out + (size_t)j * 512;
  float a0 = 0.f, a1 = 0.f, a2 = 0.f, a3 = 0.f;
  for (int k = 0; k < 512; k += 4) {
    float4 hv = *(const float4*)(hr + k);
    float4 wv = *(const float4*)(wr + k);
    a0 = fmaf(hv.x, wv.x, a0);
    a1 = fmaf(hv.y, wv.y, a1);
    a2 = fmaf(hv.z, wv.z, a2);
    a3 = fmaf(hv.w, wv.w, a3);
  }
  feats[(size_t)t * NTAG + j] = ((a0 + a1) + (a2 + a3)) + b_out[j];
}

// ---------------- kernel 4: sequential Viterbi forward (exact ops) -----------
__global__ __launch_bounds__(128) void k_viterbi(
    const float* __restrict__ feats, const float* __restrict__ trans,
    float* __restrict__ fvfinal, unsigned char* __restrict__ bps)
{
  __shared__ float fchunk[2][256 * NTAG];
  __shared__ float fv[32];
  const int tid = threadIdx.x;

  const int lo = (tid < 32) ? 1 : 0;
  const int j = (tid < 64) ? (lo ? tid : tid - 32) : 0;
  const int jc = (j < NTAG) ? j : NTAG - 1;
  const int plo = lo ? 0 : 10;
  float tr[10];
  if (tid < 64) {
#pragma unroll
    for (int q = 0; q < 10; ++q) {
      int p = plo + q;
      tr[q] = (p < NTAG) ? trans[jc * NTAG + p] : -3.0e38f;
    }
    if (tid < NTAG) fv[tid] = (tid == START_TAG) ? 0.f : -10000.f;
  }

  for (int cc = -1; cc < 32; ++cc) {
    if (tid >= 64) {
      if (cc + 1 < 32) {
        const float* src = feats + (size_t)(cc + 1) * 256 * NTAG;
        float* dst = fchunk[(cc + 1) & 1];
        for (int idx = tid - 64; idx < 256 * NTAG; idx += 64) dst[idx] = src[idx];
      }
    } else if (cc >= 0) {
      const float* fc = fchunk[cc & 1];
      for (int i = 0; i < 256; ++i) {
        float best = -3.0e38f; int bi = 0;
#pragma unroll
        for (int q = 0; q < 10; ++q) {
          int p = plo + q;
          float s = (p < NTAG) ? (fv[p] + tr[q]) : -3.0e38f;
          bool gt = s > best;              // strict >: first-max tie rule
          best = gt ? s : best;
          bi = gt ? p : bi;
        }
        float ob = __shfl_xor(best, 32);
        int obi = __shfl_xor(bi, 32);
        bool take = lo ? (ob > best) : !(best > ob);  // ties -> smaller p
        if (take) { best = ob; bi = obi; }
        int t = cc * 256 + i;
        if (tid < NTAG) {
          float fnew = best + fc[i * NTAG + tid];
          bps[(size_t)t * NTAG + tid] = (unsigned char)bi;
          fv[tid] = fnew;
        }
        __builtin_amdgcn_wave_barrier();
      }
    }
    __syncthreads();
  }
  if (tid < NTAG) fvfinal[tid] = fv[tid];
}

// ---------------- kernel 5: exact parallel backtrack via chunk composition ---
__global__ __launch_bounds__(1024) void k_backtrack(
    const float* __restrict__ fvfinal, const float* __restrict__ trans,
    const unsigned char* __restrict__ bps, float* __restrict__ out)
{
  __shared__ unsigned char maps[64][20];
  __shared__ unsigned char xc[64];
  __shared__ float score_sh;
  const int tid = threadIdx.x;

  for (int jid = tid; jid < 64 * NTAG; jid += 1024) {
    int c = jid / NTAG, tau = jid - c * NTAG;
    int y = tau;
    for (int t = (c + 1) * 128 - 1; t >= c * 128; --t)
      y = bps[(size_t)t * NTAG + y];
    maps[c][tau] = (unsigned char)y;
  }
  __syncthreads();

  if (tid == 0) {
    float best = -3.0e38f; int bi = 0;
    for (int p = 0; p < NTAG; ++p) {
      float s = fvfinal[p] + trans[STOP_TAG * NTAG + p];
      if (s > best) { best = s; bi = p; }
    }
    score_sh = best;
    int e = bi;
    for (int c = 63; c >= 0; --c) { xc[c] = (unsigned char)e; e = maps[c][e]; }
  }
  __syncthreads();

  if (tid == 0) out[0] = score_sh;
  if (tid < 64) {
    int c = tid;
    int y = xc[c];
    out[1 + ((c + 1) * 128 - 1)] = (float)y;
    for (int t = (c + 1) * 128 - 1; t > c * 128; --t) {
      y = bps[(size_t)t * NTAG + y];
      out[1 + t - 1] = (float)y;
    }
  }
}

// -----------------------------------------------------------------------------
extern "C" void kernel_launch(void* const* d_in, const int* in_sizes, int n_in,
                              void* d_out, int out_size, void* d_ws, size_t ws_size,
                              hipStream_t stream) {
  const int*   sent    = (const int*)d_in[0];
  const float* emb     = (const float*)d_in[1];
  const float* w_ih_f  = (const float*)d_in[2];
  const float* w_hh_f  = (const float*)d_in[3];
  const float* b_f     = (const float*)d_in[4];
  const float* w_ih_b  = (const float*)d_in[5];
  const float* w_hh_b  = (const float*)d_in[6];
  const float* b_b     = (const float*)d_in[7];
  const float* w_out   = (const float*)d_in[8];
  const float* b_out   = (const float*)d_in[9];
  const float* trans   = (const float*)d_in[10];
  const float* h0      = (const float*)d_in[11];
  const float* c0      = (const float*)d_in[12];
  float* out = (float*)d_out;

  char* ws = (char*)d_ws;
  float* xg            = (float*)(ws + 0);           // 2*T*1024 f32 = 64 MiB
  float* h_out         = (float*)(ws + 67108864);    // T*512 f32   = 16 MiB
  float* feats         = (float*)(ws + 83886080);    // T*19 f32
  float* fvfin         = (float*)(ws + 84508672);    // 32 f32
  unsigned char* bps   = (unsigned char*)(ws + 84508800);  // T*19 u8
  u64* hbuf            = (u64*)(ws + 84664448);      // 2 dirs * 2 slots * 256 u64

  // reset the tag words so step-tag polling starts clean every call/replay
  hipMemsetAsync(hbuf, 0, 1024 * sizeof(u64), stream);

  k_xg      <<<dim3(512, 2), 512, 0, stream>>>(sent, emb, w_ih_f, b_f, w_ih_b, b_b, xg);
  k_lstm    <<<16, 512, 0, stream>>>(xg, w_hh_f, w_hh_b, h0, c0, h_out, hbuf);
  k_feats   <<<256, 640, 0, stream>>>(h_out, w_out, b_out, feats);
  k_viterbi <<<1, 128, 0, stream>>>(feats, trans, fvfin, bps);
  k_backtrack<<<1, 1024, 0, stream>>>(fvfin, trans, bps, out);
}